// Round 2
// baseline (207.145 us; speedup 1.0000x reference)
//
#include <hip/hip_runtime.h>

#define NN      4096
#define FEAT    512
#define KDIM    576          // 512 feature cols + 64 adj_ad relation cols
#define NHID    64
#define NHEADS  8
#define NCLS    16
#define MAXDEG  128
#define ALPHA   0.2f

typedef __bf16 bf16_t;
typedef __bf16 bf16x8_t __attribute__((ext_vector_type(8)));
typedef float  f32x4_t  __attribute__((ext_vector_type(4)));
typedef unsigned short us8_t __attribute__((ext_vector_type(8)));

__device__ inline unsigned short f2bf(float f) {
    unsigned int u = __float_as_uint(f);
    u += 0x7fffu + ((u >> 16) & 1u);          // round-to-nearest-even
    return (unsigned short)(u >> 16);
}
__device__ inline float bfu2f(unsigned short b) {
    return __uint_as_float(((unsigned int)b) << 16);
}

// ---------------------------------------------------------------------------
// Fused front-end (one launch). Uses (x + adj_ad@rel)@W == x@W + adj_ad@(rel@W)
// so GEMM K-dim is extended 512->576 with A_ext=[x | adj_ad], B_ext=[W^T |
// (rel@W)^T]. The old R = adj_ad@rel dense phase is gone. Blocks:
//   [0,4096):        CSR build of adj row b (prefix-sum compaction) — adj is
//                    L3-resident across iterations (round-0 FETCH 43MB < 64MB)
//   [4096,6144):     Abf = [bf16(x) | bf16(adj_ad)] (2 rows/block); also
//                    writes the adj_ad cols of Abf2 (att1 fills cols 0..511)
//   [6144,8196):     weight permutes (pitch 576) + f1o/f2o zero-init
//   [8196,8452):     relWc = rel@Wc, relWo = rel@Wo -> B_ext rows 512..575
__global__ __launch_bounds__(256) void prep_kernel(
    const float* __restrict__ adj, int* __restrict__ deg, int* __restrict__ cols,
    const float* __restrict__ adj_ad, const float* __restrict__ rel,
    const float* __restrict__ x, bf16_t* __restrict__ Abf,
    bf16_t* __restrict__ Abf2,
    const float* __restrict__ Wh, const float* __restrict__ Wo,
    unsigned short* __restrict__ WcT, unsigned short* __restrict__ WoT,
    float* __restrict__ f1o, float* __restrict__ f2o) {
    int b = blockIdx.x;
    int t = threadIdx.x;
    __shared__ int wsum[4];
    __shared__ float srow[512];
    if (b < NN) {
        // ---- CSR via load-all + prefix-sum compaction (no atomics).
        // Thread t owns float4s {t, t+256, t+512, t+768}; cols order is
        // thread-interleaved — downstream softmax/accum are order-independent.
        const float4* row4 = (const float4*)(adj + (size_t)b * NN);
        float4 v0 = row4[t];
        float4 v1 = row4[t + 256];
        float4 v2 = row4[t + 512];
        float4 v3 = row4[t + 768];
        unsigned mask = 0;
        mask |= (v0.x > 0.0f) << 0;  mask |= (v0.y > 0.0f) << 1;
        mask |= (v0.z > 0.0f) << 2;  mask |= (v0.w > 0.0f) << 3;
        mask |= (v1.x > 0.0f) << 4;  mask |= (v1.y > 0.0f) << 5;
        mask |= (v1.z > 0.0f) << 6;  mask |= (v1.w > 0.0f) << 7;
        mask |= (v2.x > 0.0f) << 8;  mask |= (v2.y > 0.0f) << 9;
        mask |= (v2.z > 0.0f) << 10; mask |= (v2.w > 0.0f) << 11;
        mask |= (v3.x > 0.0f) << 12; mask |= (v3.y > 0.0f) << 13;
        mask |= (v3.z > 0.0f) << 14; mask |= (v3.w > 0.0f) << 15;
        int c = __popc(mask);
        int lane = t & 63;
        int pre = c;
        #pragma unroll
        for (int off = 1; off < 64; off <<= 1) {
            int n = __shfl_up(pre, off);
            if (lane >= off) pre += n;
        }
        if (lane == 63) wsum[t >> 6] = pre;
        __syncthreads();
        int base = pre - c;                      // exclusive within wave
        #pragma unroll
        for (int w2 = 0; w2 < 4; ++w2)
            if (w2 < (t >> 6)) base += wsum[w2];
        int* colrow = cols + b * MAXDEG;
        unsigned mm = mask;
        int idx = base;
        while (mm) {
            int bit = __ffs(mm) - 1;
            mm &= mm - 1;
            int j = 4 * t + (bit >> 2) * 1024 + (bit & 3);
            if (idx < MAXDEG) colrow[idx] = j;
            ++idx;
        }
        if (t == 0) {
            int tot = wsum[0] + wsum[1] + wsum[2] + wsum[3];
            deg[b] = tot > MAXDEG ? MAXDEG : tot;
        }
    } else if (b < NN + 2048) {
        // ---- A_ext cast: 2 rows per block ----
        int half = t >> 7;            // 0..1
        int tt = t & 127;
        size_t i = (size_t)(b - NN) * 2 + half;
        float4 xv = ((const float4*)(x + i * FEAT))[tt];
        ushort4 o;
        o.x = f2bf(xv.x); o.y = f2bf(xv.y);
        o.z = f2bf(xv.z); o.w = f2bf(xv.w);
        *(ushort4*)(Abf + i * KDIM + 4 * tt) = o;
        if (tt < 16) {                // 64 adj_ad cols = 16 float4
            float4 av = ((const float4*)(adj_ad + i * 64))[tt];
            ushort4 o2;
            o2.x = f2bf(av.x); o2.y = f2bf(av.y);
            o2.z = f2bf(av.z); o2.w = f2bf(av.w);
            *(ushort4*)(Abf  + i * KDIM + 512 + 4 * tt) = o2;
            *(ushort4*)(Abf2 + i * KDIM + 512 + 4 * tt) = o2;
        }
    } else if (b < NN + 2048 + 2052) {
        // ---- weight permutes (into pitch-576 B_ext) + f zero ----
        int gid = (b - NN - 2048) * 256 + t;
        if (gid < 262144) {
            int n = gid >> 9, k = gid & 511;
            int h = n >> 6, f = n & 63;
            WcT[(size_t)n * KDIM + k] = f2bf(Wh[(h * 512 + k) * 64 + f]);
        } else if (gid < 524288) {
            int idx = gid - 262144;
            int n = idx >> 9, k = idx & 511;
            WoT[(size_t)n * KDIM + k] = f2bf(Wo[k * 512 + n]);
        } else {
            int idx = gid - 524288;          // 0..1023 float4 per array
            ((float4*)f1o)[idx] = make_float4(0.f, 0.f, 0.f, 0.f);
            ((float4*)f2o)[idx] = make_float4(0.f, 0.f, 0.f, 0.f);
        }
    } else {
        // ---- relW: block = (matrix, n-half, r); 256 n's per block ----
        int rb = b - NN - 2048 - 2052;    // 0..255
        int r  = rb & 63;
        int nh = (rb >> 6) & 1;
        int n  = nh * 256 + t;
        srow[t]       = rel[r * FEAT + t];
        srow[t + 256] = rel[r * FEAT + 256 + t];
        __syncthreads();
        float acc = 0.0f;
        if (rb < 128) {               // relWc[r][n] = sum_k rel[r,k] Wh[h,k,f]
            int h = n >> 6, f = n & 63;
            const float* p = Wh + (size_t)h * 32768 + f;
            #pragma unroll 4
            for (int k = 0; k < 512; ++k) acc += srow[k] * p[(size_t)k * 64];
            WcT[(size_t)n * KDIM + 512 + r] = f2bf(acc);
        } else {                      // relWo[r][n] = sum_k rel[r,k] Wo[k,n]
            const float* p = Wo + n;
            #pragma unroll 4
            for (int k = 0; k < 512; ++k) acc += srow[k] * p[(size_t)k * 512];
            WoT[(size_t)n * KDIM + 512 + r] = f2bf(acc);
        }
    }
}

// ---------------------------------------------------------------------------
// Cbf = A @ Bt^T (bf16 in, fp32 accum, bf16 out, K=576) + fused f1/f2 dots.
// Register double-buffer: K-tile k+1 global loads issue right after the
// barrier, overlapping the MFMA loop of tile k.
__global__ __launch_bounds__(256) void gemm_bf16_dot_kernel(
    const bf16_t* __restrict__ A, const bf16_t* __restrict__ Bt,
    unsigned short* __restrict__ Cbf,
    const float* __restrict__ a1, const float* __restrict__ a2,
    float* __restrict__ f1, float* __restrict__ f2, int layer2) {
    __shared__ __align__(16) bf16_t As[64][72];   // pitch 72 elems = 144 B
    __shared__ __align__(16) bf16_t Bs[64][72];
    const int bm = blockIdx.x * 64;
    const int bn = blockIdx.y * 64;
    const int t  = threadIdx.x;
    const int lr = t >> 3;            // 0..31 staging row
    const int lc = (t & 7) * 8;       // staging col (elems)
    const int l  = t & 63;
    const int w  = t >> 6;
    const int mrow = w * 16 + (l & 15);
    const int nrow = l & 15;
    const int q8 = (l >> 4) * 8;

    const bf16_t* Ap0 = A  + (size_t)(bm + lr)      * KDIM + lc;
    const bf16_t* Ap1 = A  + (size_t)(bm + 32 + lr) * KDIM + lc;
    const bf16_t* Bp0 = Bt + (size_t)(bn + lr)      * KDIM + lc;
    const bf16_t* Bp1 = Bt + (size_t)(bn + 32 + lr) * KDIM + lc;
    uint4 ra0 = *(const uint4*)(Ap0);
    uint4 ra1 = *(const uint4*)(Ap1);
    uint4 rb0 = *(const uint4*)(Bp0);
    uint4 rb1 = *(const uint4*)(Bp1);

    f32x4_t acc[4] = {};
    for (int k0 = 0; k0 < KDIM; k0 += 64) {
        *(uint4*)&As[lr][lc]      = ra0;
        *(uint4*)&As[32 + lr][lc] = ra1;
        *(uint4*)&Bs[lr][lc]      = rb0;
        *(uint4*)&Bs[32 + lr][lc] = rb1;
        __syncthreads();
        if (k0 + 64 < KDIM) {
            ra0 = *(const uint4*)(Ap0 + k0 + 64);
            ra1 = *(const uint4*)(Ap1 + k0 + 64);
            rb0 = *(const uint4*)(Bp0 + k0 + 64);
            rb1 = *(const uint4*)(Bp1 + k0 + 64);
        }
        #pragma unroll
        for (int kk = 0; kk < 64; kk += 32) {
            bf16x8_t a = *(const bf16x8_t*)&As[mrow][kk + q8];
            #pragma unroll
            for (int nt = 0; nt < 4; ++nt) {
                bf16x8_t b = *(const bf16x8_t*)&Bs[nt * 16 + nrow][kk + q8];
                acc[nt] = __builtin_amdgcn_mfma_f32_16x16x32_bf16(a, b, acc[nt], 0, 0, 0);
            }
        }
        __syncthreads();
    }
    // C/D layout: col = lane&15, row = (lane>>4)*4 + reg
    const int crow = bm + w * 16 + (l >> 4) * 4;
    const int ccol = bn + (l & 15);
    #pragma unroll
    for (int nt = 0; nt < 4; ++nt)
        #pragma unroll
        for (int r = 0; r < 4; ++r)
            Cbf[(size_t)(crow + r) * FEAT + ccol + nt * 16] = f2bf(acc[nt][r]);

    // fused f1/f2 dots on fp32 accumulators
    float a1v[4], a2v[4];
    #pragma unroll
    for (int nt = 0; nt < 4; ++nt) {
        a1v[nt] = a1[bn + (l & 15) + nt * 16];
        a2v[nt] = a2[bn + (l & 15) + nt * 16];
    }
    float p1[4] = {}, p2[4] = {};
    #pragma unroll
    for (int nt = 0; nt < 4; ++nt)
        #pragma unroll
        for (int r = 0; r < 4; ++r) {
            p1[r] += acc[nt][r] * a1v[nt];
            p2[r] += acc[nt][r] * a2v[nt];
        }
    #pragma unroll
    for (int off = 1; off <= 8; off <<= 1)
        #pragma unroll
        for (int r = 0; r < 4; ++r) {
            p1[r] += __shfl_xor(p1[r], off);
            p2[r] += __shfl_xor(p2[r], off);
        }
    if ((l & 15) == 0) {
        int row = bm + w * 16 + (l >> 4) * 4;
        if (layer2) {
            #pragma unroll
            for (int r = 0; r < 4; ++r) {
                atomicAdd(&f1[row + r], p1[r]);
                atomicAdd(&f2[row + r], p2[r]);
            }
        } else {
            #pragma unroll
            for (int r = 0; r < 4; ++r) {
                f1[blockIdx.y * NN + row + r] = p1[r];
                f2[blockIdx.y * NN + row + r] = p2[r];
            }
        }
    }
}

// ---------------------------------------------------------------------------
// Layer-1 sparse attention + ELU epilogue -> cols 0..511 of A_ext layer 2.
// (No +R add: the relation term now rides the extended GEMM K-dim.)
__global__ __launch_bounds__(512) void att1_kernel(
    const bf16_t* __restrict__ Hbf, const float* __restrict__ f1,
    const float* __restrict__ f2, const int* __restrict__ deg,
    const int* __restrict__ cols, bf16_t* __restrict__ outbf) {
    int i = blockIdx.x;
    int tid = threadIdx.x;
    int h = tid >> 6;                 // wave id (phase A: head; phase B: slot)
    int l = tid & 63;
    __shared__ int jl[MAXDEG];
    __shared__ float se[NHEADS][MAXDEG];
    __shared__ float part[NHEADS][FEAT];   // 16 KB
    __shared__ float sinv[NHEADS];
    __shared__ int sdeg;
    if (tid == 0) sdeg = deg[i];
    __syncthreads();
    int d = sdeg;
    int dpad = (d + 31) & ~31;        // multiple of 32 (8 waves x 4 unroll)
    for (int k = tid; k < dpad; k += 512)
        jl[k] = (k < d) ? cols[i * MAXDEG + k] : i;   // pad: self, weight 0
    __syncthreads();
    // ---- phase A: scores for head h ----
    float fi = f1[h * NN + i];
    float lmax = -1e30f;
    for (int k = l; k < d; k += 64) {
        float e = fi + f2[h * NN + jl[k]];
        e = e > 0.0f ? e : ALPHA * e;
        se[h][k] = e;
        lmax = fmaxf(lmax, e);
    }
    for (int off = 32; off; off >>= 1) lmax = fmaxf(lmax, __shfl_down(lmax, off));
    float m = __shfl(lmax, 0);
    float ls = 0.0f;
    for (int k = l; k < d; k += 64) {
        float p = __expf(se[h][k] - m);
        se[h][k] = p;
        ls += p;
    }
    for (int k = d + l; k < dpad; k += 64) se[h][k] = 0.0f;
    for (int off = 32; off; off >>= 1) ls += __shfl_down(ls, off);
    if (l == 0) sinv[h] = 1.0f / ls;
    __syncthreads();                  // se/sinv now read cross-wave
    // ---- phase B: whole-row gather (wave h takes k ≡ h mod 8, unroll 4) ----
    const int myhead = l >> 3;        // head of this lane's output columns
    float acc[8] = {};
    for (int k0 = 0; k0 < dpad; k0 += 32) {
        float pw[4];
        const bf16_t* rp[4];
        #pragma unroll
        for (int j = 0; j < 4; ++j) {
            int k = k0 + j * 8 + h;                  // k < dpad guaranteed
            pw[j] = se[myhead][k];
            rp[j] = Hbf + (size_t)jl[k] * FEAT + l * 8;
        }
        #pragma unroll
        for (int j = 0; j < 4; ++j) {
            us8_t v = *(const us8_t*)rp[j];
            float p = pw[j];
            #pragma unroll
            for (int q = 0; q < 8; ++q) acc[q] += p * bfu2f(v[q]);
        }
    }
    *(float4*)&part[h][l * 8]     = make_float4(acc[0], acc[1], acc[2], acc[3]);
    *(float4*)&part[h][l * 8 + 4] = make_float4(acc[4], acc[5], acc[6], acc[7]);
    __syncthreads();
    // ---- epilogue: thread tid handles output column tid ----
    {
        float sum = 0.0f;
        #pragma unroll
        for (int w2 = 0; w2 < NHEADS; ++w2) sum += part[w2][tid];
        float o = sum * sinv[tid >> 6];
        o = o > 0.0f ? o : __expf(o) - 1.0f;         // ELU
        ((unsigned short*)outbf)[(size_t)i * KDIM + tid] = f2bf(o);
    }
}

// ---------------------------------------------------------------------------
// Layer-2 sparse attention + fused classifier + log_softmax. Block = 256.
__global__ __launch_bounds__(256) void att2_final_kernel(
    const bf16_t* __restrict__ Hbf, const float* __restrict__ f1,
    const float* __restrict__ f2, const int* __restrict__ deg,
    const int* __restrict__ cols, const float* __restrict__ linW,
    const float* __restrict__ linb, float* __restrict__ out) {
    int i = blockIdx.x;
    int t = threadIdx.x;
    __shared__ int jl[MAXDEG];
    __shared__ float sp[MAXDEG];
    __shared__ float red[4];
    __shared__ float part[3][FEAT];
    __shared__ float hrow[FEAT];
    __shared__ float clsred[16][NCLS];
    __shared__ float sl[NCLS];
    __shared__ int sdeg;
    if (t == 0) sdeg = deg[i];
    __syncthreads();
    int d = sdeg;
    int dpad = (d + 15) & ~15;        // multiple of 16 (4 waves x 4 unroll)
    if (t < dpad) jl[t] = (t < d) ? cols[i * MAXDEG + t] : i;
    __syncthreads();
    float e = 0.0f, lmax = -1e30f;
    if (t < d) {
        e = f1[i] + f2[jl[t]];
        e = e > 0.0f ? e : ALPHA * e;
        lmax = e;
    }
    for (int off = 32; off; off >>= 1) lmax = fmaxf(lmax, __shfl_down(lmax, off));
    if ((t & 63) == 0) red[t >> 6] = lmax;
    __syncthreads();
    float m = fmaxf(fmaxf(red[0], red[1]), fmaxf(red[2], red[3]));
    float p = 0.0f;
    if (t < d) p = __expf(e - m);
    if (t < dpad) sp[t] = p;          // pads write 0
    float ls = p;
    for (int off = 32; off; off >>= 1) ls += __shfl_down(ls, off);
    __syncthreads();                  // red[] reads done before overwrite
    if ((t & 63) == 0) red[t >> 6] = ls;
    __syncthreads();                  // publishes sp[] + red[]
    float s = red[0] + red[1] + red[2] + red[3];
    float inv = 1.0f / s;
    // whole-row gather, unroll 4
    const int slot = t >> 6;          // 0..3 (wave id)
    const int cg   = t & 63;          // col group (8 bf16)
    float acc[8] = {};
    for (int k0 = 0; k0 < dpad; k0 += 16) {
        float pw[4];
        const bf16_t* rp[4];
        #pragma unroll
        for (int j = 0; j < 4; ++j) {
            int k = k0 + j * 4 + slot;               // k < dpad guaranteed
            pw[j] = sp[k];
            rp[j] = Hbf + (size_t)jl[k] * FEAT + cg * 8;
        }
        #pragma unroll
        for (int j = 0; j < 4; ++j) {
            us8_t v = *(const us8_t*)rp[j];
            float pk = pw[j];
            #pragma unroll
            for (int q = 0; q < 8; ++q) acc[q] += pk * bfu2f(v[q]);
        }
    }
    // combine slots 1..3 into slot 0; slot 0 publishes h2 row to LDS
    if (slot > 0) {
        float* dst = &part[slot - 1][cg * 8];
        *(float4*)(dst)     = make_float4(acc[0], acc[1], acc[2], acc[3]);
        *(float4*)(dst + 4) = make_float4(acc[4], acc[5], acc[6], acc[7]);
    }
    __syncthreads();
    if (slot == 0) {
        #pragma unroll
        for (int sl2 = 0; sl2 < 3; ++sl2)
            #pragma unroll
            for (int j = 0; j < 8; ++j) acc[j] += part[sl2][cg * 8 + j];
        float* dst = &hrow[cg * 8];
        *(float4*)(dst)     = make_float4(acc[0] * inv, acc[1] * inv, acc[2] * inv, acc[3] * inv);
        *(float4*)(dst + 4) = make_float4(acc[4] * inv, acc[5] * inv, acc[6] * inv, acc[7] * inv);
    }
    __syncthreads();
    // classifier: class c = t&15, segment seg = t>>4 (32 features each)
    {
        int c = t & 15;
        int seg = t >> 4;
        float partial = 0.0f;
        int f0 = seg * 32;
        #pragma unroll 8
        for (int f = f0; f < f0 + 32; ++f) partial += hrow[f] * linW[f * NCLS + c];
        clsred[seg][c] = partial;
    }
    __syncthreads();
    if (t < NCLS) {
        float logit = linb[t];
        #pragma unroll
        for (int seg = 0; seg < 16; ++seg) logit += clsred[seg][t];
        logit = logit > 0.0f ? logit : __expf(logit) - 1.0f;   // ELU
        sl[t] = logit;
    }
    __syncthreads();
    if (t < NCLS) {
        float mm = sl[0];
        #pragma unroll
        for (int c = 1; c < NCLS; ++c) mm = fmaxf(mm, sl[c]);
        float ssum = 0.0f;
        #pragma unroll
        for (int c = 0; c < NCLS; ++c) ssum += __expf(sl[c] - mm);
        out[i * NCLS + t] = sl[t] - mm - logf(ssum);
    }
}

// ---------------------------------------------------------------------------
extern "C" void kernel_launch(void* const* d_in, const int* in_sizes, int n_in,
                              void* d_out, int out_size, void* d_ws, size_t ws_size,
                              hipStream_t stream) {
    const float* x        = (const float*)d_in[0];
    const float* rel      = (const float*)d_in[1];
    // d_in[2] rel_dict: unused (non-math constant per reference)
    const float* adj      = (const float*)d_in[3];
    const float* adj_ad   = (const float*)d_in[4];
    const float* W_heads  = (const float*)d_in[5];
    const float* a1_heads = (const float*)d_in[6];
    const float* a2_heads = (const float*)d_in[7];
    const float* W_out    = (const float*)d_in[8];
    const float* a1_out   = (const float*)d_in[9];
    const float* a2_out   = (const float*)d_in[10];
    const float* lin_W    = (const float*)d_in[11];
    const float* lin_b    = (const float*)d_in[12];
    float* out = (float*)d_out;

    char* ws = (char*)d_ws;
    bf16_t* Abf  = (bf16_t*)(ws);                                 // 4.5 MB [4096][576] layer-1 A_ext
    bf16_t* Abf2 = (bf16_t*)(ws + (5u  << 20));                   // 4.5 MB [4096][576] layer-2 A_ext
    bf16_t* Hbf1 = (bf16_t*)(ws + (10u << 20));                   // 4 MB  [4096][512] layer-1 H (gather)
    bf16_t* Hbf2 = (bf16_t*)(ws + (14u << 20));                   // 4 MB  [4096][512] layer-2 H (gather)
    bf16_t* WcT  = (bf16_t*)(ws + (18u << 20));                   // 576 KB [512][576] B_ext layer 1
    bf16_t* WoT  = (bf16_t*)(ws + (19u << 20));                   // 576 KB [512][576] B_ext layer 2
    float*  f1   = (float*) (ws + (20u << 20));                   // 128 KB [8,4096]
    float*  f2   = (float*) (ws + (20u << 20) + (128u << 10));    // 128 KB
    float*  f1o  = (float*) (ws + (20u << 20) + (256u << 10));    // 16 KB
    float*  f2o  = (float*) (ws + (20u << 20) + (272u << 10));    // 16 KB
    int*    deg  = (int*)   (ws + (20u << 20) + (288u << 10));    // 16 KB
    int*    cols = (int*)   (ws + (21u << 20));                   // 2 MB  [4096,128]

    // fused front-end: CSR + A_ext casts + weight permutes + rel@W + f-zero
    prep_kernel<<<NN + 2048 + 2052 + 256, 256, 0, stream>>>(
        adj, deg, cols, adj_ad, rel, x, Abf, Abf2, W_heads, W_out,
        (unsigned short*)WcT, (unsigned short*)WoT, f1o, f2o);
    // layer-1 GEMM (K=576) + fused f1/f2 dots (direct store)
    gemm_bf16_dot_kernel<<<dim3(64, 8), 256, 0, stream>>>(
        Abf, WcT, (unsigned short*)Hbf1, a1_heads, a2_heads, f1, f2, 0);
    // layer-1 attention + ELU epilogue -> Abf2 cols 0..511
    att1_kernel<<<NN, 512, 0, stream>>>(Hbf1, f1, f2, deg, cols, Abf2);
    // layer-2 GEMM (K=576) + fused f1o/f2o dots (atomicAdd across bn blocks)
    gemm_bf16_dot_kernel<<<dim3(64, 8), 256, 0, stream>>>(
        Abf2, WoT, (unsigned short*)Hbf2, a1_out, a2_out, f1o, f2o, 1);
    // layer-2 attention + classifier + log_softmax -> out (fused)
    att2_final_kernel<<<NN, 256, 0, stream>>>(Hbf2, f1o, f2o, deg, cols, lin_W, lin_b, out);
}

// Round 4
// 188.421 us; speedup vs baseline: 1.0994x; 1.0994x over previous
//
#include <hip/hip_runtime.h>

#define NN      4096
#define FEAT    512
#define KDIM    576          // 512 feature cols + 64 adj_ad relation cols
#define NHID    64
#define NHEADS  8
#define NCLS    16
#define MAXDEG  128
#define ALPHA   0.2f

typedef __bf16 bf16_t;
typedef __bf16 bf16x8_t __attribute__((ext_vector_type(8)));
typedef float  f32x4_t  __attribute__((ext_vector_type(4)));
typedef unsigned short us8_t __attribute__((ext_vector_type(8)));

__device__ inline unsigned short f2bf(float f) {
    unsigned int u = __float_as_uint(f);
    u += 0x7fffu + ((u >> 16) & 1u);          // round-to-nearest-even
    return (unsigned short)(u >> 16);
}
__device__ inline float bfu2f(unsigned short b) {
    return __uint_as_float(((unsigned int)b) << 16);
}

// ---------------------------------------------------------------------------
// Fused front-end (one launch). Uses (x + adj_ad@rel)@W == x@W + adj_ad@(rel@W)
// so GEMM K-dim is 576 with A_ext=[x | adj_ad], B_ext=[W^T | (rel@W)^T].
// Phase order puts latency-bound low-parallelism work FIRST so it hides under
// the big CSR stream (round-2 lesson: relW as grid-tail cost ~5-10us serial):
//   [0,256):      relW  (rel@Wc, rel@Wo -> B_ext rows 512..575), 8-way ILP
//   [256,384):    weight transposes via LDS 64x64 tiles (coalesced both sides)
//   [384,392):    f1o/f2o zero
//   [392,2440):   A_ext cast rows (x, adj_ad -> bf16, pitch 576)
//   [2440,3464):  CSR: ONE WAVE PER ROW, no barriers/LDS, 16 loads in flight
#define PREP_REL0   0
#define PREP_TR0    256
#define PREP_Z0     384
#define PREP_CAST0  392
#define PREP_CSR0   2440
#define PREP_NBLK   3464

__global__ __launch_bounds__(256) void prep_kernel(
    const float* __restrict__ adj, int* __restrict__ deg, int* __restrict__ cols,
    const float* __restrict__ adj_ad, const float* __restrict__ rel,
    const float* __restrict__ x, bf16_t* __restrict__ Abf,
    bf16_t* __restrict__ Abf2,
    const float* __restrict__ Wh, const float* __restrict__ Wo,
    unsigned short* __restrict__ WcT, unsigned short* __restrict__ WoT,
    float* __restrict__ f1o, float* __restrict__ f2o) {
    int b = blockIdx.x;
    int t = threadIdx.x;
    __shared__ float smem[64 * 65];       // relW: srow[512]; transpose: tile
    if (b < PREP_TR0) {
        // ---- relW: block = (matrix(1b), n-half(1b), r(6b)); 256 n's/block --
        int r  = b & 63;
        int nh = (b >> 6) & 1;
        int n  = nh * 256 + t;
        smem[t]       = rel[r * FEAT + t];
        smem[t + 256] = rel[r * FEAT + 256 + t];
        __syncthreads();
        float acc[8] = {};
        if (b < 128) {                // relWc[r][n] = sum_k rel[r,k] Wh[h,k,f]
            int h = n >> 6, f = n & 63;
            const float* p = Wh + (size_t)h * 32768 + f;
            for (int k0 = 0; k0 < 512; k0 += 8)
                #pragma unroll
                for (int u = 0; u < 8; ++u)
                    acc[u] += smem[k0 + u] * p[(size_t)(k0 + u) * 64];
            float s = ((acc[0] + acc[1]) + (acc[2] + acc[3]))
                    + ((acc[4] + acc[5]) + (acc[6] + acc[7]));
            WcT[(size_t)n * KDIM + 512 + r] = f2bf(s);
        } else {                      // relWo[r][n] = sum_k rel[r,k] Wo[k,n]
            const float* p = Wo + n;
            for (int k0 = 0; k0 < 512; k0 += 8)
                #pragma unroll
                for (int u = 0; u < 8; ++u)
                    acc[u] += smem[k0 + u] * p[(size_t)(k0 + u) * 512];
            float s = ((acc[0] + acc[1]) + (acc[2] + acc[3]))
                    + ((acc[4] + acc[5]) + (acc[6] + acc[7]));
            WoT[(size_t)n * KDIM + 512 + r] = f2bf(s);
        }
    } else if (b < PREP_Z0) {
        // ---- weight transposes: 64x64 LDS tile, coalesced load AND store --
        int tb = b - PREP_TR0;        // 0..127: [0,64) Wc, [64,128) Wo
        if (tb < 64) {
            // WcT[(h*64+f)*KDIM + k] = Wh[h*32768 + k*64 + f]
            int h = tb >> 3, k0 = (tb & 7) * 64;
            const float* src = Wh + (size_t)h * 32768 + (size_t)k0 * 64;
            #pragma unroll
            for (int i2 = 0; i2 < 16; ++i2) {
                int li = t + i2 * 256;            // r = li>>6, f = li&63
                float v = src[li];                // contiguous
                smem[(li & 63) * 65 + (li >> 6)] = v;   // tile[f][r]
            }
            __syncthreads();
            #pragma unroll
            for (int i2 = 0; i2 < 16; ++i2) {
                int li = t + i2 * 256;
                int f = li >> 6, r = li & 63;
                WcT[(size_t)(h * 64 + f) * KDIM + k0 + r] = f2bf(smem[f * 65 + r]);
            }
        } else {
            // WoT[(n)*KDIM + k] = Wo[k*512 + n]
            int wb = tb - 64;
            int n0 = (wb & 7) * 64, k0 = (wb >> 3) * 64;
            #pragma unroll
            for (int i2 = 0; i2 < 16; ++i2) {
                int li = t + i2 * 256;            // r = li>>6 (k), f = li&63 (n)
                int r = li >> 6, f = li & 63;
                float v = Wo[(size_t)(k0 + r) * 512 + n0 + f];   // coalesced
                smem[f * 65 + r] = v;
            }
            __syncthreads();
            #pragma unroll
            for (int i2 = 0; i2 < 16; ++i2) {
                int li = t + i2 * 256;
                int f = li >> 6, r = li & 63;
                WoT[(size_t)(n0 + f) * KDIM + k0 + r] = f2bf(smem[f * 65 + r]);
            }
        }
    } else if (b < PREP_CAST0) {
        // ---- f1o/f2o zero: 8 blocks x 256 threads = 2048 float4 ----
        int g = (b - PREP_Z0) * 256 + t;
        if (g < 1024) ((float4*)f1o)[g] = make_float4(0.f, 0.f, 0.f, 0.f);
        else ((float4*)f2o)[g - 1024] = make_float4(0.f, 0.f, 0.f, 0.f);
    } else if (b < PREP_CSR0) {
        // ---- A_ext cast: 2 rows per block ----
        int half = t >> 7;            // 0..1
        int tt = t & 127;
        size_t i = (size_t)(b - PREP_CAST0) * 2 + half;
        float4 xv = ((const float4*)(x + i * FEAT))[tt];
        ushort4 o;
        o.x = f2bf(xv.x); o.y = f2bf(xv.y);
        o.z = f2bf(xv.z); o.w = f2bf(xv.w);
        *(ushort4*)(Abf + i * KDIM + 4 * tt) = o;
        if (tt < 16) {                // 64 adj_ad cols = 16 float4
            float4 av = ((const float4*)(adj_ad + i * 64))[tt];
            ushort4 o2;
            o2.x = f2bf(av.x); o2.y = f2bf(av.y);
            o2.z = f2bf(av.z); o2.w = f2bf(av.w);
            *(ushort4*)(Abf  + i * KDIM + 512 + 4 * tt) = o2;
            *(ushort4*)(Abf2 + i * KDIM + 512 + 4 * tt) = o2;
        }
    } else {
        // ---- CSR: one WAVE per row. 16 float4 loads in flight per lane,
        // 64-bit lane mask, wave prefix-sum, scatter. No barriers, no LDS.
        // cols order is lane-interleaved — downstream sums are order-indep.
        int l = t & 63;
        int i = (b - PREP_CSR0) * 4 + (t >> 6);
        const float4* row4 = (const float4*)(adj + (size_t)i * NN);
        float4 v[16];
        #pragma unroll
        for (int c2 = 0; c2 < 16; ++c2) v[c2] = row4[l + c2 * 64];
        unsigned long long mask = 0;
        #pragma unroll
        for (int c2 = 0; c2 < 16; ++c2) {
            unsigned m4 = (unsigned)(v[c2].x > 0.0f)
                        | ((unsigned)(v[c2].y > 0.0f) << 1)
                        | ((unsigned)(v[c2].z > 0.0f) << 2)
                        | ((unsigned)(v[c2].w > 0.0f) << 3);
            mask |= (unsigned long long)m4 << (4 * c2);
        }
        int c = __popcll(mask);
        int pre = c;
        #pragma unroll
        for (int off = 1; off < 64; off <<= 1) {
            int n = __shfl_up(pre, off);
            if (l >= off) pre += n;
        }
        int base = pre - c;           // exclusive prefix within wave
        if (l == 63) deg[i] = pre > MAXDEG ? MAXDEG : pre;
        int* colrow = cols + i * MAXDEG;
        int idx = base;
        while (mask) {
            int bit = (int)__ffsll(mask) - 1;
            mask &= mask - 1;
            int j = 4 * l + ((bit >> 2) << 8) + (bit & 3);
            if (idx < MAXDEG) colrow[idx] = j;
            ++idx;
        }
    }
}

// ---------------------------------------------------------------------------
// Cbf = A @ Bt^T (bf16 in, fp32 accum, bf16 out, K=576) + fused f1/f2 dots.
// Register double-buffer: K-tile k+1 global loads issue right after the
// barrier, overlapping the MFMA loop of tile k.
__global__ __launch_bounds__(256) void gemm_bf16_dot_kernel(
    const bf16_t* __restrict__ A, const bf16_t* __restrict__ Bt,
    unsigned short* __restrict__ Cbf,
    const float* __restrict__ a1, const float* __restrict__ a2,
    float* __restrict__ f1, float* __restrict__ f2, int layer2) {
    __shared__ __align__(16) bf16_t As[64][72];   // pitch 72 elems = 144 B
    __shared__ __align__(16) bf16_t Bs[64][72];
    const int bm = blockIdx.x * 64;
    const int bn = blockIdx.y * 64;
    const int t  = threadIdx.x;
    const int lr = t >> 3;            // 0..31 staging row
    const int lc = (t & 7) * 8;       // staging col (elems)
    const int l  = t & 63;
    const int w  = t >> 6;
    const int mrow = w * 16 + (l & 15);
    const int nrow = l & 15;
    const int q8 = (l >> 4) * 8;

    const bf16_t* Ap0 = A  + (size_t)(bm + lr)      * KDIM + lc;
    const bf16_t* Ap1 = A  + (size_t)(bm + 32 + lr) * KDIM + lc;
    const bf16_t* Bp0 = Bt + (size_t)(bn + lr)      * KDIM + lc;
    const bf16_t* Bp1 = Bt + (size_t)(bn + 32 + lr) * KDIM + lc;
    uint4 ra0 = *(const uint4*)(Ap0);
    uint4 ra1 = *(const uint4*)(Ap1);
    uint4 rb0 = *(const uint4*)(Bp0);
    uint4 rb1 = *(const uint4*)(Bp1);

    f32x4_t acc[4] = {};
    for (int k0 = 0; k0 < KDIM; k0 += 64) {
        *(uint4*)&As[lr][lc]      = ra0;
        *(uint4*)&As[32 + lr][lc] = ra1;
        *(uint4*)&Bs[lr][lc]      = rb0;
        *(uint4*)&Bs[32 + lr][lc] = rb1;
        __syncthreads();
        if (k0 + 64 < KDIM) {
            ra0 = *(const uint4*)(Ap0 + k0 + 64);
            ra1 = *(const uint4*)(Ap1 + k0 + 64);
            rb0 = *(const uint4*)(Bp0 + k0 + 64);
            rb1 = *(const uint4*)(Bp1 + k0 + 64);
        }
        #pragma unroll
        for (int kk = 0; kk < 64; kk += 32) {
            bf16x8_t a = *(const bf16x8_t*)&As[mrow][kk + q8];
            #pragma unroll
            for (int nt = 0; nt < 4; ++nt) {
                bf16x8_t b = *(const bf16x8_t*)&Bs[nt * 16 + nrow][kk + q8];
                acc[nt] = __builtin_amdgcn_mfma_f32_16x16x32_bf16(a, b, acc[nt], 0, 0, 0);
            }
        }
        __syncthreads();
    }
    // C/D layout: col = lane&15, row = (lane>>4)*4 + reg
    const int crow = bm + w * 16 + (l >> 4) * 4;
    const int ccol = bn + (l & 15);
    #pragma unroll
    for (int nt = 0; nt < 4; ++nt)
        #pragma unroll
        for (int r = 0; r < 4; ++r)
            Cbf[(size_t)(crow + r) * FEAT + ccol + nt * 16] = f2bf(acc[nt][r]);

    // fused f1/f2 dots on fp32 accumulators
    float a1v[4], a2v[4];
    #pragma unroll
    for (int nt = 0; nt < 4; ++nt) {
        a1v[nt] = a1[bn + (l & 15) + nt * 16];
        a2v[nt] = a2[bn + (l & 15) + nt * 16];
    }
    float p1[4] = {}, p2[4] = {};
    #pragma unroll
    for (int nt = 0; nt < 4; ++nt)
        #pragma unroll
        for (int r = 0; r < 4; ++r) {
            p1[r] += acc[nt][r] * a1v[nt];
            p2[r] += acc[nt][r] * a2v[nt];
        }
    #pragma unroll
    for (int off = 1; off <= 8; off <<= 1)
        #pragma unroll
        for (int r = 0; r < 4; ++r) {
            p1[r] += __shfl_xor(p1[r], off);
            p2[r] += __shfl_xor(p2[r], off);
        }
    if ((l & 15) == 0) {
        int row = bm + w * 16 + (l >> 4) * 4;
        if (layer2) {
            #pragma unroll
            for (int r = 0; r < 4; ++r) {
                atomicAdd(&f1[row + r], p1[r]);
                atomicAdd(&f2[row + r], p2[r]);
            }
        } else {
            #pragma unroll
            for (int r = 0; r < 4; ++r) {
                f1[blockIdx.y * NN + row + r] = p1[r];
                f2[blockIdx.y * NN + row + r] = p2[r];
            }
        }
    }
}

// ---------------------------------------------------------------------------
// Layer-1 sparse attention + ELU epilogue -> cols 0..511 of A_ext layer 2.
__global__ __launch_bounds__(512) void att1_kernel(
    const bf16_t* __restrict__ Hbf, const float* __restrict__ f1,
    const float* __restrict__ f2, const int* __restrict__ deg,
    const int* __restrict__ cols, bf16_t* __restrict__ outbf) {
    int i = blockIdx.x;
    int tid = threadIdx.x;
    int h = tid >> 6;                 // wave id (phase A: head; phase B: slot)
    int l = tid & 63;
    __shared__ int jl[MAXDEG];
    __shared__ float se[NHEADS][MAXDEG];
    __shared__ float part[NHEADS][FEAT];   // 16 KB
    __shared__ float sinv[NHEADS];
    __shared__ int sdeg;
    if (tid == 0) sdeg = deg[i];
    __syncthreads();
    int d = sdeg;
    int dpad = (d + 31) & ~31;        // multiple of 32 (8 waves x 4 unroll)
    for (int k = tid; k < dpad; k += 512)
        jl[k] = (k < d) ? cols[i * MAXDEG + k] : i;   // pad: self, weight 0
    __syncthreads();
    // ---- phase A: scores for head h ----
    float fi = f1[h * NN + i];
    float lmax = -1e30f;
    for (int k = l; k < d; k += 64) {
        float e = fi + f2[h * NN + jl[k]];
        e = e > 0.0f ? e : ALPHA * e;
        se[h][k] = e;
        lmax = fmaxf(lmax, e);
    }
    for (int off = 32; off; off >>= 1) lmax = fmaxf(lmax, __shfl_down(lmax, off));
    float m = __shfl(lmax, 0);
    float ls = 0.0f;
    for (int k = l; k < d; k += 64) {
        float p = __expf(se[h][k] - m);
        se[h][k] = p;
        ls += p;
    }
    for (int k = d + l; k < dpad; k += 64) se[h][k] = 0.0f;
    for (int off = 32; off; off >>= 1) ls += __shfl_down(ls, off);
    if (l == 0) sinv[h] = 1.0f / ls;
    __syncthreads();                  // se/sinv now read cross-wave
    // ---- phase B: whole-row gather (wave h takes k ≡ h mod 8, unroll 4) ----
    const int myhead = l >> 3;        // head of this lane's output columns
    float acc[8] = {};
    for (int k0 = 0; k0 < dpad; k0 += 32) {
        float pw[4];
        const bf16_t* rp[4];
        #pragma unroll
        for (int j = 0; j < 4; ++j) {
            int k = k0 + j * 8 + h;                  // k < dpad guaranteed
            pw[j] = se[myhead][k];
            rp[j] = Hbf + (size_t)jl[k] * FEAT + l * 8;
        }
        #pragma unroll
        for (int j = 0; j < 4; ++j) {
            us8_t v = *(const us8_t*)rp[j];
            float p = pw[j];
            #pragma unroll
            for (int q = 0; q < 8; ++q) acc[q] += p * bfu2f(v[q]);
        }
    }
    *(float4*)&part[h][l * 8]     = make_float4(acc[0], acc[1], acc[2], acc[3]);
    *(float4*)&part[h][l * 8 + 4] = make_float4(acc[4], acc[5], acc[6], acc[7]);
    __syncthreads();
    // ---- epilogue: thread tid handles output column tid ----
    {
        float sum = 0.0f;
        #pragma unroll
        for (int w2 = 0; w2 < NHEADS; ++w2) sum += part[w2][tid];
        float o = sum * sinv[tid >> 6];
        o = o > 0.0f ? o : __expf(o) - 1.0f;         // ELU
        ((unsigned short*)outbf)[(size_t)i * KDIM + tid] = f2bf(o);
    }
}

// ---------------------------------------------------------------------------
// Layer-2 sparse attention + fused classifier + log_softmax. Block = 256.
__global__ __launch_bounds__(256) void att2_final_kernel(
    const bf16_t* __restrict__ Hbf, const float* __restrict__ f1,
    const float* __restrict__ f2, const int* __restrict__ deg,
    const int* __restrict__ cols, const float* __restrict__ linW,
    const float* __restrict__ linb, float* __restrict__ out) {
    int i = blockIdx.x;
    int t = threadIdx.x;
    __shared__ int jl[MAXDEG];
    __shared__ float sp[MAXDEG];
    __shared__ float red[4];
    __shared__ float part[3][FEAT];
    __shared__ float hrow[FEAT];
    __shared__ float clsred[16][NCLS];
    __shared__ float sl[NCLS];
    __shared__ int sdeg;
    if (t == 0) sdeg = deg[i];
    __syncthreads();
    int d = sdeg;
    int dpad = (d + 15) & ~15;        // multiple of 16 (4 waves x 4 unroll)
    if (t < dpad) jl[t] = (t < d) ? cols[i * MAXDEG + t] : i;
    __syncthreads();
    float e = 0.0f, lmax = -1e30f;
    if (t < d) {
        e = f1[i] + f2[jl[t]];
        e = e > 0.0f ? e : ALPHA * e;
        lmax = e;
    }
    for (int off = 32; off; off >>= 1) lmax = fmaxf(lmax, __shfl_down(lmax, off));
    if ((t & 63) == 0) red[t >> 6] = lmax;
    __syncthreads();
    float m = fmaxf(fmaxf(red[0], red[1]), fmaxf(red[2], red[3]));
    float p = 0.0f;
    if (t < d) p = __expf(e - m);
    if (t < dpad) sp[t] = p;          // pads write 0
    float ls = p;
    for (int off = 32; off; off >>= 1) ls += __shfl_down(ls, off);
    __syncthreads();                  // red[] reads done before overwrite
    if ((t & 63) == 0) red[t >> 6] = ls;
    __syncthreads();                  // publishes sp[] + red[]
    float s = red[0] + red[1] + red[2] + red[3];
    float inv = 1.0f / s;
    // whole-row gather, unroll 4
    const int slot = t >> 6;          // 0..3 (wave id)
    const int cg   = t & 63;          // col group (8 bf16)
    float acc[8] = {};
    for (int k0 = 0; k0 < dpad; k0 += 16) {
        float pw[4];
        const bf16_t* rp[4];
        #pragma unroll
        for (int j = 0; j < 4; ++j) {
            int k = k0 + j * 4 + slot;               // k < dpad guaranteed
            pw[j] = sp[k];
            rp[j] = Hbf + (size_t)jl[k] * FEAT + cg * 8;
        }
        #pragma unroll
        for (int j = 0; j < 4; ++j) {
            us8_t v = *(const us8_t*)rp[j];
            float pk = pw[j];
            #pragma unroll
            for (int q = 0; q < 8; ++q) acc[q] += pk * bfu2f(v[q]);
        }
    }
    // combine slots 1..3 into slot 0; slot 0 publishes h2 row to LDS
    if (slot > 0) {
        float* dst = &part[slot - 1][cg * 8];
        *(float4*)(dst)     = make_float4(acc[0], acc[1], acc[2], acc[3]);
        *(float4*)(dst + 4) = make_float4(acc[4], acc[5], acc[6], acc[7]);
    }
    __syncthreads();
    if (slot == 0) {
        #pragma unroll
        for (int sl2 = 0; sl2 < 3; ++sl2)
            #pragma unroll
            for (int j = 0; j < 8; ++j) acc[j] += part[sl2][cg * 8 + j];
        float* dst = &hrow[cg * 8];
        *(float4*)(dst)     = make_float4(acc[0] * inv, acc[1] * inv, acc[2] * inv, acc[3] * inv);
        *(float4*)(dst + 4) = make_float4(acc[4] * inv, acc[5] * inv, acc[6] * inv, acc[7] * inv);
    }
    __syncthreads();
    // classifier: class c = t&15, segment seg = t>>4 (32 features each)
    {
        int c = t & 15;
        int seg = t >> 4;
        float partial = 0.0f;
        int f0 = seg * 32;
        #pragma unroll 8
        for (int f = f0; f < f0 + 32; ++f) partial += hrow[f] * linW[f * NCLS + c];
        clsred[seg][c] = partial;
    }
    __syncthreads();
    if (t < NCLS) {
        float logit = linb[t];
        #pragma unroll
        for (int seg = 0; seg < 16; ++seg) logit += clsred[seg][t];
        logit = logit > 0.0f ? logit : __expf(logit) - 1.0f;   // ELU
        sl[t] = logit;
    }
    __syncthreads();
    if (t < NCLS) {
        float mm = sl[0];
        #pragma unroll
        for (int c = 1; c < NCLS; ++c) mm = fmaxf(mm, sl[c]);
        float ssum = 0.0f;
        #pragma unroll
        for (int c = 0; c < NCLS; ++c) ssum += __expf(sl[c] - mm);
        out[i * NCLS + t] = sl[t] - mm - logf(ssum);
    }
}

// ---------------------------------------------------------------------------
extern "C" void kernel_launch(void* const* d_in, const int* in_sizes, int n_in,
                              void* d_out, int out_size, void* d_ws, size_t ws_size,
                              hipStream_t stream) {
    const float* x        = (const float*)d_in[0];
    const float* rel      = (const float*)d_in[1];
    // d_in[2] rel_dict: unused (non-math constant per reference)
    const float* adj      = (const float*)d_in[3];
    const float* adj_ad   = (const float*)d_in[4];
    const float* W_heads  = (const float*)d_in[5];
    const float* a1_heads = (const float*)d_in[6];
    const float* a2_heads = (const float*)d_in[7];
    const float* W_out    = (const float*)d_in[8];
    const float* a1_out   = (const float*)d_in[9];
    const float* a2_out   = (const float*)d_in[10];
    const float* lin_W    = (const float*)d_in[11];
    const float* lin_b    = (const float*)d_in[12];
    float* out = (float*)d_out;

    char* ws = (char*)d_ws;
    bf16_t* Abf  = (bf16_t*)(ws);                                 // 4.5 MB [4096][576] layer-1 A_ext
    bf16_t* Abf2 = (bf16_t*)(ws + (5u  << 20));                   // 4.5 MB [4096][576] layer-2 A_ext
    bf16_t* Hbf1 = (bf16_t*)(ws + (10u << 20));                   // 4 MB  [4096][512] layer-1 H (gather)
    bf16_t* Hbf2 = (bf16_t*)(ws + (14u << 20));                   // 4 MB  [4096][512] layer-2 H (gather)
    bf16_t* WcT  = (bf16_t*)(ws + (18u << 20));                   // 576 KB [512][576] B_ext layer 1
    bf16_t* WoT  = (bf16_t*)(ws + (19u << 20));                   // 576 KB [512][576] B_ext layer 2
    float*  f1   = (float*) (ws + (20u << 20));                   // 128 KB [8,4096]
    float*  f2   = (float*) (ws + (20u << 20) + (128u << 10));    // 128 KB
    float*  f1o  = (float*) (ws + (20u << 20) + (256u << 10));    // 16 KB
    float*  f2o  = (float*) (ws + (20u << 20) + (272u << 10));    // 16 KB
    int*    deg  = (int*)   (ws + (20u << 20) + (288u << 10));    // 16 KB
    int*    cols = (int*)   (ws + (21u << 20));                   // 2 MB  [4096,128]

    // fused front-end: relW + transposes + zero + A_ext casts + CSR
    prep_kernel<<<PREP_NBLK, 256, 0, stream>>>(
        adj, deg, cols, adj_ad, rel, x, Abf, Abf2, W_heads, W_out,
        (unsigned short*)WcT, (unsigned short*)WoT, f1o, f2o);
    // layer-1 GEMM (K=576) + fused f1/f2 dots (direct store)
    gemm_bf16_dot_kernel<<<dim3(64, 8), 256, 0, stream>>>(
        Abf, WcT, (unsigned short*)Hbf1, a1_heads, a2_heads, f1, f2, 0);
    // layer-1 attention + ELU epilogue -> Abf2 cols 0..511
    att1_kernel<<<NN, 512, 0, stream>>>(Hbf1, f1, f2, deg, cols, Abf2);
    // layer-2 GEMM (K=576) + fused f1o/f2o dots (atomicAdd across bn blocks)
    gemm_bf16_dot_kernel<<<dim3(64, 8), 256, 0, stream>>>(
        Abf2, WoT, (unsigned short*)Hbf2, a1_out, a2_out, f1o, f2o, 1);
    // layer-2 attention + classifier + log_softmax -> out (fused)
    att2_final_kernel<<<NN, 256, 0, stream>>>(Hbf2, f1o, f2o, deg, cols, lin_W, lin_b, out);
}